// Round 2
// baseline (16191.164 us; speedup 1.0000x reference)
//
#include <hip/hip_runtime.h>
#include <hip/hip_bf16.h>
#include <math.h>

#define B_      2
#define N_      2048
#define DIM_    1024
#define HEADS_  16
#define DH_     64
#define ROWS_   4096      // B*N
#define DCOND_  4096
#define DFF_    2730
#define DFF1_   5460
#define NFOUR_  1025
#define SCALE_  0.125f
#define TWO_PI_ 6.28318530717958647692f

// ---------------------------------------------------------------- fourier
__global__ __launch_bounds__(256) void fourier_kernel(const float* __restrict__ times,
                                                      const float* __restrict__ fw,
                                                      float* __restrict__ F) {
  int r = blockIdx.x;                 // 0..4095
  float tv = times[r];
  float* Fr = F + (size_t)r * NFOUR_;
  if (threadIdx.x == 0) Fr[0] = tv;
  for (int j = threadIdx.x; j < 512; j += 256) {
    float f = tv * fw[j] * TWO_PI_;
    Fr[1 + j]   = sinf(f);
    Fr[513 + j] = cosf(f);
  }
}

// ---------------------------------------------------------------- generic GEMM
// C[M,Nc] = A[M,K](fp32) * W[K,Nc](fp32) (+bias, epilogue)
// mode: 0 = none, 1 = +bias, 2 = silu(+bias), 3 = sigmoid(+bias)
#define BM 64
#define BN 64
#define BK 16
__global__ __launch_bounds__(256) void gemm_kernel(
    const float* __restrict__ A, const float* __restrict__ W,
    const float* __restrict__ bias, float* __restrict__ C,
    int K, int Nc, int mode)
{
  __shared__ float As[BK][BM + 1];   // +1 pad: conflict-free column store
  __shared__ float Bs[BK][BN];
  int tid = threadIdx.x;
  int tx = tid & 15, ty = tid >> 4;
  int bm = blockIdx.y * BM;
  int bn = blockIdx.x * BN;
  float c[4][4] = {{0.f}};
  int ktiles = (K + BK - 1) / BK;
  for (int kt = 0; kt < ktiles; ++kt) {
    int k0 = kt * BK;
#pragma unroll
    for (int i = 0; i < 4; ++i) {
      int e = tid + i * 256;           // 0..1023
      int mm = e >> 4, kk = e & 15;    // coalesced along k
      int k = k0 + kk;
      As[kk][mm] = (k < K) ? A[(size_t)(bm + mm) * K + k] : 0.f;
    }
#pragma unroll
    for (int i = 0; i < 4; ++i) {
      int e = tid + i * 256;
      int kk = e >> 6, nn = e & 63;    // coalesced along n
      int k = k0 + kk, n = bn + nn;
      Bs[kk][nn] = (k < K && n < Nc) ? W[(size_t)k * Nc + n] : 0.f;
    }
    __syncthreads();
#pragma unroll
    for (int kk = 0; kk < BK; ++kk) {
      float4 bv = *(const float4*)&Bs[kk][tx * 4];
      float aa[4], bb[4] = {bv.x, bv.y, bv.z, bv.w};
#pragma unroll
      for (int i = 0; i < 4; ++i) aa[i] = As[kk][ty * 4 + i];
#pragma unroll
      for (int i = 0; i < 4; ++i)
#pragma unroll
        for (int j = 0; j < 4; ++j)
          c[i][j] = fmaf(aa[i], bb[j], c[i][j]);
    }
    __syncthreads();
  }
#pragma unroll
  for (int i = 0; i < 4; ++i) {
    int m = bm + ty * 4 + i;
#pragma unroll
    for (int j = 0; j < 4; ++j) {
      int n = bn + tx * 4 + j;
      if (n >= Nc) continue;
      float v = c[i][j];
      if (mode >= 1) v += bias[n];
      if (mode == 2)      v = v / (1.f + __expf(-v));   // silu
      else if (mode == 3) v = 1.f / (1.f + __expf(-v)); // sigmoid
      C[(size_t)m * Nc + n] = v;
    }
  }
}

// ---------------------------------------------------------------- masks
__global__ __launch_bounds__(256) void ismod_kernel(const int* __restrict__ mp,
                                                    float* __restrict__ ismod) {
  int idx = blockIdx.x * 256 + threadIdx.x;   // 0..4095
  int b = idx >> 11, n = idx & 2047;
  const int* p = mp + b * 6;
  bool m = false;
#pragma unroll
  for (int mi = 0; mi < 2; ++mi) {
    int off = p[mi * 3 + 1], len = p[mi * 3 + 2];
    m = m || ((n >= off) && (n < off + len));
  }
  ismod[idx] = m ? 1.f : 0.f;
}

// ---------------------------------------------------------------- layernorm (no affine)
__global__ __launch_bounds__(256) void layernorm_kernel(const float* __restrict__ X,
                                                        float* __restrict__ Y) {
  int r = blockIdx.x;
  const float* xr = X + (size_t)r * DIM_;
  float s = 0.f, ss = 0.f;
  for (int c = threadIdx.x; c < DIM_; c += 256) { float v = xr[c]; s += v; ss += v * v; }
#pragma unroll
  for (int o = 32; o > 0; o >>= 1) { s += __shfl_down(s, o); ss += __shfl_down(ss, o); }
  __shared__ float shs[4], shss[4];
  int w = threadIdx.x >> 6;
  if ((threadIdx.x & 63) == 0) { shs[w] = s; shss[w] = ss; }
  __syncthreads();
  float tot = shs[0] + shs[1] + shs[2] + shs[3];
  float tots = shss[0] + shss[1] + shss[2] + shss[3];
  float mu = tot * (1.f / DIM_);
  float var = tots * (1.f / DIM_) - mu * mu;
  float rstd = rsqrtf(var + 1e-5f);
  for (int c = threadIdx.x; c < DIM_; c += 256)
    Y[(size_t)r * DIM_ + c] = (xr[c] - mu) * rstd;
}

// ---------------------------------------------------------------- film modulate (in place on H)
__global__ __launch_bounds__(256) void modulate_kernel(float* __restrict__ H,
                                                       const float* __restrict__ film,
                                                       const float* __restrict__ lng,
                                                       const float* __restrict__ ismod) {
  int idx = blockIdx.x * 256 + threadIdx.x;  // ROWS_*DIM_
  int r = idx >> 10, c = idx & 1023;
  float h = H[idx];
  float g = film[(size_t)r * 2048 + c];
  float bt = film[(size_t)r * 2048 + 1024 + c];
  float out = (ismod[r] != 0.f) ? (h * (g + 1.f) + bt) : (h * (lng[c] + 1.f));
  H[idx] = out;
}

// ---------------------------------------------------------------- rmsnorm
__global__ __launch_bounds__(256) void rmsnorm_kernel(const float* __restrict__ X,
                                                      const float* __restrict__ g,
                                                      float* __restrict__ Y) {
  int r = blockIdx.x;
  const float* xr = X + (size_t)r * DIM_;
  float ss = 0.f;
  for (int c = threadIdx.x; c < DIM_; c += 256) { float v = xr[c]; ss += v * v; }
#pragma unroll
  for (int o = 32; o > 0; o >>= 1) ss += __shfl_down(ss, o);
  __shared__ float shss[4];
  int w = threadIdx.x >> 6;
  if ((threadIdx.x & 63) == 0) shss[w] = ss;
  __syncthreads();
  float tots = shss[0] + shss[1] + shss[2] + shss[3];
  float scale = 32.f / fmaxf(sqrtf(tots), 1e-12f);   // sqrt(1024)=32
  for (int c = threadIdx.x; c < DIM_; c += 256)
    Y[(size_t)r * DIM_ + c] = xr[c] * scale * (g[c] + 1.f);
}

// ---------------------------------------------------------------- rotary on q,k of qkv [ROWS_,3072]
__global__ __launch_bounds__(256) void rotary_kernel(float* __restrict__ QKV,
                                                     const float* __restrict__ rot) {
  int idx = blockIdx.x * 256 + threadIdx.x;  // ROWS_ * 1024 pairs
  int r = idx >> 10;
  int c0 = (idx & 1023) * 2;                 // 0..2046 (q then k)
  int n = r & 2047;
  int d = c0 & 63;
  float f = rot[n * 64 + d];
  float cs = cosf(f), sn = sinf(f);
  float* p = QKV + (size_t)r * 3072 + c0;
  float x0 = p[0], x1 = p[1];
  p[0] = x0 * cs - x1 * sn;
  p[1] = x1 * cs + x0 * sn;
}

// ---------------------------------------------------------------- attention (online softmax, softcap, mask)
__global__ __launch_bounds__(256, 1) void attn_kernel(const float* __restrict__ QKV,
                                                      const int* __restrict__ mp,
                                                      float* __restrict__ O) {
  __shared__ float Ks[64][64];
  __shared__ float Vs[64][64];
  int bh = blockIdx.y;
  int b = bh >> 4, h = bh & 15;
  int i = blockIdx.x * 256 + threadIdx.x;   // query index in sequence
  int r = b * N_ + i;
  int off0 = mp[b * 6 + 1], end0 = off0 + mp[b * 6 + 2];
  int off1 = mp[b * 6 + 4], end1 = off1 + mp[b * 6 + 5];
  float q[64];
  {
    const float* qrow = QKV + (size_t)r * 3072 + h * 64;
#pragma unroll
    for (int d = 0; d < 64; ++d) q[d] = qrow[d] * SCALE_;
  }
  float m = -3.4e38f, l = 0.f;
  float o[64];
#pragma unroll
  for (int d = 0; d < 64; ++d) o[d] = 0.f;

  for (int jt = 0; jt < N_ / 64; ++jt) {
    __syncthreads();
    for (int e = threadIdx.x; e < 4096; e += 256) {
      int jj = e >> 6, d = e & 63;
      const float* krow = QKV + (size_t)(b * N_ + jt * 64 + jj) * 3072 + h * 64 + d;
      Ks[jj][d] = krow[1024];
      Vs[jj][d] = krow[2048];
    }
    __syncthreads();
    for (int jj = 0; jj < 64; ++jj) {
      int j = jt * 64 + jj;
      bool ok = (i >= j) || ((i >= off0) && (j < end0)) || ((i >= off1) && (j < end1));
      if (!ok) continue;
      float s0 = 0.f, s1 = 0.f, s2 = 0.f, s3 = 0.f;
#pragma unroll
      for (int d = 0; d < 64; d += 4) {
        s0 = fmaf(q[d + 0], Ks[jj][d + 0], s0);
        s1 = fmaf(q[d + 1], Ks[jj][d + 1], s1);
        s2 = fmaf(q[d + 2], Ks[jj][d + 2], s2);
        s3 = fmaf(q[d + 3], Ks[jj][d + 3], s3);
      }
      float s = (s0 + s1) + (s2 + s3);
      s = tanhf(s * (1.f / 50.f)) * 50.f;
      float mn = fmaxf(m, s);
      float sc = __expf(m - mn);
      float p = __expf(s - mn);
      l = l * sc + p;
#pragma unroll
      for (int d = 0; d < 64; ++d) o[d] = fmaf(p, Vs[jj][d], o[d] * sc);
      m = mn;
    }
  }
  float inv = 1.f / l;
  float* orow = O + (size_t)r * 1024 + h * 64;
#pragma unroll
  for (int d = 0; d < 64; ++d) orow[d] = o[d] * inv;
}

// ---------------------------------------------------------------- geglu (exact gelu)
__global__ __launch_bounds__(256) void geglu_kernel(const float* __restrict__ FF1,
                                                    float* __restrict__ MID) {
  int c = blockIdx.x * 256 + threadIdx.x;
  int r = blockIdx.y;
  if (c >= DFF_) return;
  float u = FF1[(size_t)r * DFF1_ + c];
  float g = FF1[(size_t)r * DFF1_ + DFF_ + c];
  float ge = 0.5f * g * (1.f + erff(g * 0.70710678118654752440f));
  MID[(size_t)r * DFF_ + c] = ge * u;
}

// ---------------------------------------------------------------- residual: X += select(out*gate, out*(ls+1))
__global__ __launch_bounds__(256) void residual_kernel(float* __restrict__ X,
                                                       const float* __restrict__ outb,
                                                       const float* __restrict__ gate,
                                                       const float* __restrict__ ls,
                                                       const float* __restrict__ ismod) {
  int idx = blockIdx.x * 256 + threadIdx.x;
  int r = idx >> 10, c = idx & 1023;
  float ov = outb[idx];
  float v = (ismod[r] != 0.f) ? (ov * gate[idx]) : (ov * (ls[c] + 1.f));
  X[idx] += v;
}

// ================================================================ launch
extern "C" void kernel_launch(void* const* d_in, const int* in_sizes, int n_in,
                              void* d_out, int out_size, void* d_ws, size_t ws_size,
                              hipStream_t stream) {
  const float* in_x   = (const float*)d_in[0];
  const float* times  = (const float*)d_in[1];
  const float* rotary = (const float*)d_in[2];
  const float* fwgt   = (const float*)d_in[3];
  const float* time_w = (const float*)d_in[4];
  const float* time_b = (const float*)d_in[5];
  const float* afw    = (const float*)d_in[6];
  const float* afb    = (const float*)d_in[7];
  const float* azw    = (const float*)d_in[8];
  const float* azb    = (const float*)d_in[9];
  const float* alng   = (const float*)d_in[10];
  const float* als    = (const float*)d_in[11];
  const float* armsg  = (const float*)d_in[12];
  const float* wqkv   = (const float*)d_in[13];
  const float* wout   = (const float*)d_in[14];
  const float* ffw    = (const float*)d_in[15];
  const float* ffb    = (const float*)d_in[16];
  const float* fzw    = (const float*)d_in[17];
  const float* fzb    = (const float*)d_in[18];
  const float* flng   = (const float*)d_in[19];
  const float* fls    = (const float*)d_in[20];
  const float* frmsg  = (const float*)d_in[21];
  const float* fw1    = (const float*)d_in[22];
  const float* fb1    = (const float*)d_in[23];
  const float* fw2    = (const float*)d_in[24];
  const float* fb2    = (const float*)d_in[25];
  const float* fing   = (const float*)d_in[26];
  const int*   mp     = (const int*)d_in[27];
  float* out = (float*)d_out;

  float* ws      = (float*)d_ws;
  float* f_x     = ws;                       // 4,194,304
  float* f_cond  = f_x    + 4194304;         // 16,777,216
  float* f_h     = f_cond + 16777216;        // 4,194,304
  float* f_film  = f_h    + 4194304;         // 8,388,608
  float* f_big   = f_film + 8388608;         // 12,582,912 (fourier / qkv / ff1-chunk / gate)
  float* f_mid   = f_big  + 12582912;        // 11,182,080 (attn-out / geglu-out)
  float* f_ismod = f_mid  + 11182080;        // 4,096

  // conditioning
  fourier_kernel<<<ROWS_, 256, 0, stream>>>(times, fwgt, f_big);
  gemm_kernel<<<dim3(DCOND_ / 64, ROWS_ / 64), 256, 0, stream>>>(
      f_big, time_w, time_b, f_cond, NFOUR_, DCOND_, 2);
  ismod_kernel<<<ROWS_ / 256, 256, 0, stream>>>(mp, f_ismod);
  hipMemcpyAsync(f_x, in_x, (size_t)ROWS_ * DIM_ * sizeof(float),
                 hipMemcpyDeviceToDevice, stream);

  for (int l = 0; l < 2; ++l) {
    // ---- attention block ----
    layernorm_kernel<<<ROWS_, 256, 0, stream>>>(f_x, f_h);
    gemm_kernel<<<dim3(2048 / 64, 64), 256, 0, stream>>>(
        f_cond, afw + (size_t)l * DCOND_ * 2048, afb + l * 2048, f_film, DCOND_, 2048, 1);
    modulate_kernel<<<(ROWS_ * DIM_) / 256, 256, 0, stream>>>(f_h, f_film, alng + l * 1024, f_ismod);
    rmsnorm_kernel<<<ROWS_, 256, 0, stream>>>(f_h, armsg + l * 1024, f_h);
    gemm_kernel<<<dim3(3072 / 64, 64), 256, 0, stream>>>(
        f_h, wqkv + (size_t)l * 1024 * 3072, nullptr, f_big, 1024, 3072, 0);
    rotary_kernel<<<(ROWS_ * 1024) / 256, 256, 0, stream>>>(f_big, rotary);
    attn_kernel<<<dim3(8, 32), 256, 0, stream>>>(f_big, mp, f_mid);
    gemm_kernel<<<dim3(16, 64), 256, 0, stream>>>(
        f_mid, wout + (size_t)l * 1024 * 1024, nullptr, f_film, 1024, 1024, 0);
    gemm_kernel<<<dim3(16, 64), 256, 0, stream>>>(
        f_cond, azw + (size_t)l * DCOND_ * 1024, azb + l * 1024, f_big, DCOND_, 1024, 3);
    residual_kernel<<<(ROWS_ * DIM_) / 256, 256, 0, stream>>>(f_x, f_film, f_big, als + l * 1024, f_ismod);

    // ---- feed-forward block ----
    layernorm_kernel<<<ROWS_, 256, 0, stream>>>(f_x, f_h);
    gemm_kernel<<<dim3(2048 / 64, 64), 256, 0, stream>>>(
        f_cond, ffw + (size_t)l * DCOND_ * 2048, ffb + l * 2048, f_film, DCOND_, 2048, 1);
    modulate_kernel<<<(ROWS_ * DIM_) / 256, 256, 0, stream>>>(f_h, f_film, flng + l * 1024, f_ismod);
    rmsnorm_kernel<<<ROWS_, 256, 0, stream>>>(f_h, frmsg + l * 1024, f_h);
    for (int rc = 0; rc < 4; ++rc) {   // row-chunked ff1 to bound ws
      gemm_kernel<<<dim3((DFF1_ + 63) / 64, 16), 256, 0, stream>>>(
          f_h + (size_t)rc * 1024 * 1024, fw1 + (size_t)l * 1024 * DFF1_, fb1 + l * DFF1_,
          f_big, 1024, DFF1_, 1);
      geglu_kernel<<<dim3((DFF_ + 255) / 256, 1024), 256, 0, stream>>>(
          f_big, f_mid + (size_t)rc * 1024 * DFF_);
    }
    gemm_kernel<<<dim3(16, 64), 256, 0, stream>>>(
        f_mid, fw2 + (size_t)l * DFF_ * 1024, fb2 + l * 1024, f_film, DFF_, 1024, 1);
    gemm_kernel<<<dim3(16, 64), 256, 0, stream>>>(
        f_cond, fzw + (size_t)l * DCOND_ * 1024, fzb + l * 1024, f_big, DCOND_, 1024, 3);
    residual_kernel<<<(ROWS_ * DIM_) / 256, 256, 0, stream>>>(f_x, f_film, f_big, fls + l * 1024, f_ismod);
  }

  // final norm -> fp32 out
  rmsnorm_kernel<<<ROWS_, 256, 0, stream>>>(f_x, fing, out);
}

// Round 4
// 4499.622 us; speedup vs baseline: 3.5983x; 3.5983x over previous
//
#include <hip/hip_runtime.h>
#include <math.h>

#define B_      2
#define N_      2048
#define DIM_    1024
#define ROWS_   4096      // B*N
#define DCOND_  4096
#define DFF_    2730
#define DFF1_   5460
#define KF_     1056      // fourier K padded (1025 -> 1056)
#define KM_     2752      // geglu-mid K padded (2730 -> 2752)
#define SCALE_  0.125f
#define TWO_PI_ 6.28318530717958647692f

typedef __attribute__((ext_vector_type(8))) short bfx8;   // 8 bf16 = 4 VGPR
typedef __attribute__((ext_vector_type(4))) float fx4;    // MFMA accum

__device__ __forceinline__ float b2f(unsigned short u) {
  return __uint_as_float(((unsigned)u) << 16);
}
__device__ __forceinline__ unsigned short f2b(float f) {  // RNE
  unsigned x = __float_as_uint(f);
  return (unsigned short)((x + 0x7FFF + ((x >> 16) & 1)) >> 16);
}

// ---------------------------------------------------------------- fourier -> bf16 [4096][1056], zero-padded
__global__ __launch_bounds__(256) void fourier_kernel(const float* __restrict__ times,
                                                      const float* __restrict__ fw,
                                                      unsigned short* __restrict__ F) {
  int r = blockIdx.x;
  float tv = times[r];
  unsigned short* Fr = F + (size_t)r * KF_;
  for (int c = threadIdx.x; c < KF_; c += 256) {
    float v;
    if (c == 0)          v = tv;
    else if (c <= 512)   v = sinf(tv * fw[c - 1] * TWO_PI_);
    else if (c <= 1024)  v = cosf(tv * fw[c - 513] * TWO_PI_);
    else                 v = 0.f;
    Fr[c] = f2b(v);
  }
}

// ---------------------------------------------------------------- weight transpose: W f32 [K][N] -> WT bf16 [N][KP] (zero pad k>=K)
__global__ __launch_bounds__(256) void transpose_w(const float* __restrict__ W,
                                                   unsigned short* __restrict__ WT,
                                                   int K, int N, int KP) {
  __shared__ float t[32][33];
  int tx = threadIdx.x, ty = threadIdx.y;    // 32 x 8
  int k0 = blockIdx.x * 32, n0 = blockIdx.y * 32;
#pragma unroll
  for (int i = 0; i < 4; ++i) {
    int k = k0 + ty + i * 8, n = n0 + tx;
    t[ty + i * 8][tx] = (k < K && n < N) ? W[(size_t)k * N + n] : 0.f;
  }
  __syncthreads();
#pragma unroll
  for (int i = 0; i < 4; ++i) {
    int n = n0 + ty + i * 8;
    if (n < N) WT[(size_t)n * KP + k0 + tx] = f2b(t[tx][ty + i * 8]);
  }
}

// ---------------------------------------------------------------- MFMA GEMM: C[M][Nc] = A_bf16[M][K] * BT_bf16[Npad][K]
// Staging via explicit b128 load + ds_write (no global_load_lds this round — bisect).
// mode: 0 none, 1 +bias, 2 silu(+bias), 3 sigmoid(+bias); out_bf: 1 -> bf16 C, 0 -> f32 C
__global__ __launch_bounds__(256) void mfma_gemm(const unsigned short* __restrict__ A,
                                                 const unsigned short* __restrict__ BT,
                                                 const float* __restrict__ bias,
                                                 void* __restrict__ Cout,
                                                 int K, int Nc, int mode, int out_bf) {
  __shared__ unsigned short As[128 * 32];
  __shared__ unsigned short Bs[128 * 32];
  int tid = threadIdx.x;
  int wave = tid >> 6, lane = tid & 63;
  int bm = blockIdx.y * 128, bn = blockIdx.x * 128;
  int wm = (wave >> 1) * 64, wn = (wave & 1) * 64;
  int lr = lane >> 4, lc = lane & 15;
  fx4 acc[4][4];
#pragma unroll
  for (int i = 0; i < 4; ++i)
#pragma unroll
    for (int j = 0; j < 4; ++j) acc[i][j] = (fx4){0.f, 0.f, 0.f, 0.f};

  for (int k0 = 0; k0 < K; k0 += 32) {
    // 512 chunks of 8 bf16 (16B) per matrix; chunk c -> row c>>2, k-sub (c&3)*8
#pragma unroll
    for (int i = 0; i < 2; ++i) {
      int c = tid + i * 256;
      int row = c >> 2, kc = (c & 3) * 8;
      bfx8 av = *(const bfx8*)(A  + (size_t)(bm + row) * K + k0 + kc);
      bfx8 bv = *(const bfx8*)(BT + (size_t)(bn + row) * K + k0 + kc);
      *(bfx8*)&As[c * 8] = av;
      *(bfx8*)&Bs[c * 8] = bv;
    }
    __syncthreads();
    bfx8 af[4], bf[4];
#pragma unroll
    for (int mi = 0; mi < 4; ++mi)
      af[mi] = *(const bfx8*)&As[(wm + mi * 16 + lc) * 32 + lr * 8];
#pragma unroll
    for (int ni = 0; ni < 4; ++ni)
      bf[ni] = *(const bfx8*)&Bs[(wn + ni * 16 + lc) * 32 + lr * 8];
#pragma unroll
    for (int mi = 0; mi < 4; ++mi)
#pragma unroll
      for (int ni = 0; ni < 4; ++ni)
        acc[mi][ni] = __builtin_amdgcn_mfma_f32_16x16x32_bf16(af[mi], bf[ni], acc[mi][ni], 0, 0, 0);
    __syncthreads();
  }
  // epilogue: C/D layout col=lane&15, row=(lane>>4)*4+reg  [measured m89/m91]
#pragma unroll
  for (int mi = 0; mi < 4; ++mi) {
#pragma unroll
    for (int ni = 0; ni < 4; ++ni) {
      int col = bn + wn + ni * 16 + lc;
      if (col >= Nc) continue;
      float bv = (mode >= 1) ? bias[col] : 0.f;
#pragma unroll
      for (int r = 0; r < 4; ++r) {
        int row = bm + wm + mi * 16 + lr * 4 + r;
        float v = acc[mi][ni][r] + bv;
        if (mode == 2)      v = v / (1.f + __expf(-v));
        else if (mode == 3) v = 1.f / (1.f + __expf(-v));
        if (out_bf) ((unsigned short*)Cout)[(size_t)row * Nc + col] = f2b(v);
        else        ((float*)Cout)[(size_t)row * Nc + col] = v;
      }
    }
  }
}

// ---------------------------------------------------------------- ismod
__global__ __launch_bounds__(256) void ismod_kernel(const int* __restrict__ mp,
                                                    float* __restrict__ ismod) {
  int idx = blockIdx.x * 256 + threadIdx.x;
  int b = idx >> 11, n = idx & 2047;
  const int* p = mp + b * 6;
  bool m = false;
#pragma unroll
  for (int mi = 0; mi < 2; ++mi) {
    int off = p[mi * 3 + 1], len = p[mi * 3 + 2];
    m = m || ((n >= off) && (n < off + len));
  }
  ismod[idx] = m ? 1.f : 0.f;
}

// ---------------------------------------------------------------- layernorm f32->f32
__global__ __launch_bounds__(256) void layernorm_kernel(const float* __restrict__ X,
                                                        float* __restrict__ Y) {
  int r = blockIdx.x;
  const float* xr = X + (size_t)r * DIM_;
  float s = 0.f, ss = 0.f;
  for (int c = threadIdx.x; c < DIM_; c += 256) { float v = xr[c]; s += v; ss += v * v; }
#pragma unroll
  for (int o = 32; o > 0; o >>= 1) { s += __shfl_down(s, o); ss += __shfl_down(ss, o); }
  __shared__ float shs[4], shss[4];
  int w = threadIdx.x >> 6;
  if ((threadIdx.x & 63) == 0) { shs[w] = s; shss[w] = ss; }
  __syncthreads();
  float mu = (shs[0] + shs[1] + shs[2] + shs[3]) * (1.f / DIM_);
  float var = (shss[0] + shss[1] + shss[2] + shss[3]) * (1.f / DIM_) - mu * mu;
  float rstd = rsqrtf(var + 1e-5f);
  for (int c = threadIdx.x; c < DIM_; c += 256)
    Y[(size_t)r * DIM_ + c] = (xr[c] - mu) * rstd;
}

// ---------------------------------------------------------------- modulate (H f32 in place; film f32 [r][2048])
__global__ __launch_bounds__(256) void modulate_kernel(float* __restrict__ H,
                                                       const float* __restrict__ film,
                                                       const float* __restrict__ lng,
                                                       const float* __restrict__ ismod) {
  int idx = blockIdx.x * 256 + threadIdx.x;
  int r = idx >> 10, c = idx & 1023;
  float h = H[idx];
  float g = film[(size_t)r * 2048 + c];
  float bt = film[(size_t)r * 2048 + 1024 + c];
  H[idx] = (ismod[r] != 0.f) ? (h * (g + 1.f) + bt) : (h * (lng[c] + 1.f));
}

// ---------------------------------------------------------------- rmsnorm (Yb bf16 or Yf f32)
__global__ __launch_bounds__(256) void rmsnorm_kernel(const float* __restrict__ X,
                                                      const float* __restrict__ g,
                                                      unsigned short* __restrict__ Yb,
                                                      float* __restrict__ Yf) {
  int r = blockIdx.x;
  const float* xr = X + (size_t)r * DIM_;
  float ss = 0.f;
  for (int c = threadIdx.x; c < DIM_; c += 256) { float v = xr[c]; ss += v * v; }
#pragma unroll
  for (int o = 32; o > 0; o >>= 1) ss += __shfl_down(ss, o);
  __shared__ float shss[4];
  int w = threadIdx.x >> 6;
  if ((threadIdx.x & 63) == 0) shss[w] = ss;
  __syncthreads();
  float tots = shss[0] + shss[1] + shss[2] + shss[3];
  float scale = 32.f / fmaxf(sqrtf(tots), 1e-12f);
  for (int c = threadIdx.x; c < DIM_; c += 256) {
    float v = xr[c] * scale * (g[c] + 1.f);
    if (Yb) Yb[(size_t)r * DIM_ + c] = f2b(v);
    else    Yf[(size_t)r * DIM_ + c] = v;
  }
}

// ---------------------------------------------------------------- rotary on f32 qkv [ROWS_][3072] (q,k halves)
__global__ __launch_bounds__(256) void rotary_kernel(float* __restrict__ QKV,
                                                     const float* __restrict__ rot) {
  int idx = blockIdx.x * 256 + threadIdx.x;   // ROWS_*1024 pairs
  int r = idx >> 10;
  int c0 = (idx & 1023) * 2;                  // 0..2046
  float f = rot[(r & 2047) * 64 + (c0 & 63)];
  float cs = cosf(f), sn = sinf(f);
  float* p = QKV + (size_t)r * 3072 + c0;
  float x0 = p[0], x1 = p[1];
  p[0] = x0 * cs - x1 * sn;
  p[1] = x1 * cs + x0 * sn;
}

// ---------------------------------------------------------------- attention: 4 threads/query, f32 in, bf16 out
__global__ __launch_bounds__(256) void attn_kernel(const float* __restrict__ QKV,
                                                   const int* __restrict__ mp,
                                                   unsigned short* __restrict__ O) {
  __shared__ float Ks[64 * 64];
  __shared__ float Vs[64 * 64];
  int bh = blockIdx.y;
  int b = bh >> 4, h = bh & 15;
  int qb = blockIdx.x;
  int tid = threadIdx.x;
  int qi = tid >> 2, sl = tid & 3, d0 = sl * 16;
  int i = qb * 64 + qi;
  int r = b * N_ + i;
  int off0 = mp[b * 6 + 1], end0 = off0 + mp[b * 6 + 2];
  int off1 = mp[b * 6 + 4], end1 = off1 + mp[b * 6 + 5];
  int qmax = qb * 64 + 63;
  float q[16], o[16];
  const float* qrow = QKV + (size_t)r * 3072 + h * 64 + d0;
#pragma unroll
  for (int d = 0; d < 16; ++d) { q[d] = qrow[d] * SCALE_; o[d] = 0.f; }
  float m = -3.4e38f, l = 0.f;

  for (int jt = 0; jt < 32; ++jt) {
    int j0 = jt * 64;
    // block-uniform tile skip
    if (!((j0 <= qmax) || (qmax >= off0 && j0 < end0) || (qmax >= off1 && j0 < end1))) continue;
    __syncthreads();
    for (int e = tid; e < 1024; e += 256) {     // 64 rows x 16 float4-chunks each
      int jj = e >> 4, dc = (e & 15) * 4;
      const float* kr = QKV + (size_t)(b * N_ + j0 + jj) * 3072 + h * 64 + dc;
      *(float4*)&Ks[jj * 64 + dc] = *(const float4*)(kr + 1024);
      *(float4*)&Vs[jj * 64 + dc] = *(const float4*)(kr + 2048);
    }
    __syncthreads();
    for (int jj = 0; jj < 64; ++jj) {
      int j = j0 + jj;
      bool ok = (i >= j) || (i >= off0 && j < end0) || (i >= off1 && j < end1);
      if (!ok) continue;
      const float* kp = &Ks[jj * 64 + d0];
      float s = 0.f;
#pragma unroll
      for (int t = 0; t < 16; ++t) s = fmaf(q[t], kp[t], s);
      s += __shfl_xor(s, 1);
      s += __shfl_xor(s, 2);
      float xc = fminf(fmaxf(s * 0.02f, -15.f), 15.f);   // s/50, clamped (tanh saturated)
      float e2 = __expf(2.f * xc);
      s = 50.f * (e2 - 1.f) / (e2 + 1.f);
      float mn = fmaxf(m, s);
      float scl = __expf(m - mn);
      float p = __expf(s - mn);
      l = l * scl + p;
      const float* vp = &Vs[jj * 64 + d0];
#pragma unroll
      for (int t = 0; t < 16; ++t) o[t] = fmaf(p, vp[t], o[t] * scl);
      m = mn;
    }
  }
  float inv = 1.f / l;
  unsigned short* orow = O + (size_t)r * 1024 + h * 64 + d0;
#pragma unroll
  for (int d = 0; d < 16; ++d) orow[d] = f2b(o[d] * inv);
}

// ---------------------------------------------------------------- geglu: ff1 chunk f32 [1024][5460] -> mid bf16 rows (stride 2752, zero pad)
__global__ __launch_bounds__(256) void geglu_kernel(const float* __restrict__ FF1,
                                                    unsigned short* __restrict__ MID) {
  int c = blockIdx.x * 256 + threadIdx.x;
  int r = blockIdx.y;
  if (c >= KM_) return;
  unsigned short outv = 0;
  if (c < DFF_) {
    float u = FF1[(size_t)r * DFF1_ + c];
    float g = FF1[(size_t)r * DFF1_ + DFF_ + c];
    float ge = 0.5f * g * (1.f + erff(g * 0.70710678118654752440f));
    outv = f2b(ge * u);
  }
  MID[(size_t)r * KM_ + c] = outv;
}

// ---------------------------------------------------------------- residual: X += select(out*gate, out*(ls+1))
__global__ __launch_bounds__(256) void residual_kernel(float* __restrict__ X,
                                                       const float* __restrict__ outb,
                                                       const float* __restrict__ gate,
                                                       const float* __restrict__ ls,
                                                       const float* __restrict__ ismod) {
  int idx = blockIdx.x * 256 + threadIdx.x;
  int r = idx >> 10, c = idx & 1023;
  float ov = outb[idx];
  float v = (ismod[r] != 0.f) ? (ov * gate[idx]) : (ov * (ls[c] + 1.f));
  X[idx] += v;
}

// ================================================================ launch
extern "C" void kernel_launch(void* const* d_in, const int* in_sizes, int n_in,
                              void* d_out, int out_size, void* d_ws, size_t ws_size,
                              hipStream_t stream) {
  const float* in_x   = (const float*)d_in[0];
  const float* times  = (const float*)d_in[1];
  const float* rotary = (const float*)d_in[2];
  const float* fwgt   = (const float*)d_in[3];
  const float* time_w = (const float*)d_in[4];
  const float* time_b = (const float*)d_in[5];
  const float* afw    = (const float*)d_in[6];
  const float* afb    = (const float*)d_in[7];
  const float* azw    = (const float*)d_in[8];
  const float* azb    = (const float*)d_in[9];
  const float* alng   = (const float*)d_in[10];
  const float* als    = (const float*)d_in[11];
  const float* armsg  = (const float*)d_in[12];
  const float* wqkv   = (const float*)d_in[13];
  const float* wout   = (const float*)d_in[14];
  const float* ffw    = (const float*)d_in[15];
  const float* ffb    = (const float*)d_in[16];
  const float* fzw    = (const float*)d_in[17];
  const float* fzb    = (const float*)d_in[18];
  const float* flng   = (const float*)d_in[19];
  const float* fls    = (const float*)d_in[20];
  const float* frmsg  = (const float*)d_in[21];
  const float* fw1    = (const float*)d_in[22];
  const float* fb1    = (const float*)d_in[23];
  const float* fw2    = (const float*)d_in[24];
  const float* fb2    = (const float*)d_in[25];
  const float* fing   = (const float*)d_in[26];
  const int*   mp     = (const int*)d_in[27];
  float* out = (float*)d_out;

  char* p = (char*)d_ws;
  unsigned short* wT   = (unsigned short*)p;      p += 17301504;
  float* f_x           = (float*)p;               p += 16777216;
  float* f_ln          = (float*)p;               p += 16777216;
  float* f_o           = (float*)p;               p += 16777216;
  unsigned short* cond = (unsigned short*)p;      p += 33554432;  // [4096][4096] bf16
  unsigned short* hbf  = (unsigned short*)p;      p += 8388608;   // [4096][1024] bf16
  float* film          = (float*)p;               p += 33554432;  // [4096][2048] f32
  float* gate          = (float*)p;               p += 16777216;  // [4096][1024] f32
  char* arena          = p;                       p += 58720256;
  float* f_ismod       = (float*)p;               p += 16384;

  float* qkv             = (float*)arena;                      // [4096][3072] f32
  unsigned short* attno  = (unsigned short*)(arena + 50331648);// [4096][1024] bf16
  float* ff1c            = (float*)arena;                      // [1024][5460] f32 chunk
  unsigned short* mid    = (unsigned short*)(arena + 22364160);// [4096][2752] bf16
  unsigned short* four   = (unsigned short*)arena;             // [4096][1056] bf16

  auto gemm = [&](const unsigned short* A, const float* bias, void* C,
                  int K, int Nc, int mode, int out_bf, int mtiles) {
    mfma_gemm<<<dim3((Nc + 127) / 128, mtiles), 256, 0, stream>>>(A, wT, bias, C, K, Nc, mode, out_bf);
  };
  auto transp = [&](const float* W, int K, int N, int KP) {
    transpose_w<<<dim3(KP / 32, (N + 31) / 32), dim3(32, 8), 0, stream>>>(W, wT, K, N, KP);
  };

  // ---- conditioning ----
  fourier_kernel<<<ROWS_, 256, 0, stream>>>(times, fwgt, four);
  transp(time_w, 1025, DCOND_, KF_);
  gemm(four, time_b, cond, KF_, DCOND_, 2, 1, 32);               // cond = silu(...) bf16
  ismod_kernel<<<ROWS_ / 256, 256, 0, stream>>>(mp, f_ismod);
  hipMemcpyAsync(f_x, in_x, (size_t)ROWS_ * DIM_ * sizeof(float),
                 hipMemcpyDeviceToDevice, stream);

  for (int l = 0; l < 2; ++l) {
    // ---- attention block ----
    layernorm_kernel<<<ROWS_, 256, 0, stream>>>(f_x, f_ln);
    transp(afw + (size_t)l * DCOND_ * 2048, DCOND_, 2048, DCOND_);
    gemm(cond, afb + l * 2048, film, DCOND_, 2048, 1, 0, 32);
    modulate_kernel<<<(ROWS_ * DIM_) / 256, 256, 0, stream>>>(f_ln, film, alng + l * 1024, f_ismod);
    rmsnorm_kernel<<<ROWS_, 256, 0, stream>>>(f_ln, armsg + l * 1024, hbf, nullptr);
    transp(wqkv + (size_t)l * 1024 * 3072, 1024, 3072, 1024);
    gemm(hbf, nullptr, qkv, 1024, 3072, 0, 0, 32);
    rotary_kernel<<<(ROWS_ * 1024) / 256, 256, 0, stream>>>(qkv, rotary);
    attn_kernel<<<dim3(32, 32), 256, 0, stream>>>(qkv, mp, attno);
    transp(wout + (size_t)l * 1024 * 1024, 1024, 1024, 1024);
    gemm(attno, nullptr, f_o, 1024, 1024, 0, 0, 32);
    transp(azw + (size_t)l * DCOND_ * 1024, DCOND_, 1024, DCOND_);
    gemm(cond, azb + l * 1024, gate, DCOND_, 1024, 3, 0, 32);
    residual_kernel<<<(ROWS_ * DIM_) / 256, 256, 0, stream>>>(f_x, f_o, gate, als + l * 1024, f_ismod);

    // ---- feed-forward block ----
    layernorm_kernel<<<ROWS_, 256, 0, stream>>>(f_x, f_ln);
    transp(ffw + (size_t)l * DCOND_ * 2048, DCOND_, 2048, DCOND_);
    gemm(cond, ffb + l * 2048, film, DCOND_, 2048, 1, 0, 32);
    modulate_kernel<<<(ROWS_ * DIM_) / 256, 256, 0, stream>>>(f_ln, film, flng + l * 1024, f_ismod);
    rmsnorm_kernel<<<ROWS_, 256, 0, stream>>>(f_ln, frmsg + l * 1024, hbf, nullptr);
    transp(fw1 + (size_t)l * 1024 * DFF1_, 1024, DFF1_, 1024);
    for (int rc = 0; rc < 4; ++rc) {
      gemm(hbf + (size_t)rc * 1024 * 1024, fb1 + l * DFF1_, ff1c, 1024, DFF1_, 1, 0, 8);
      geglu_kernel<<<dim3((KM_ + 255) / 256, 1024), 256, 0, stream>>>(
          ff1c, mid + (size_t)rc * 1024 * KM_);
    }
    transp(fw2 + (size_t)l * DFF_ * 1024, DFF_, 1024, KM_);
    gemm(mid, fb2 + l * 1024, f_o, KM_, 1024, 1, 0, 32);
    transp(fzw + (size_t)l * DCOND_ * 1024, DCOND_, 1024, DCOND_);
    gemm(cond, fzb + l * 1024, gate, DCOND_, 1024, 3, 0, 32);
    residual_kernel<<<(ROWS_ * DIM_) / 256, 256, 0, stream>>>(f_x, f_o, gate, fls + l * 1024, f_ismod);
  }

  // final rmsnorm -> fp32 out
  rmsnorm_kernel<<<ROWS_, 256, 0, stream>>>(f_x, fing, nullptr, out);
}

// Round 5
// 2630.248 us; speedup vs baseline: 6.1558x; 1.7107x over previous
//
#include <hip/hip_runtime.h>
#include <math.h>

#define B_      2
#define N_      2048
#define DIM_    1024
#define ROWS_   4096      // B*N
#define DCOND_  4096
#define DFF_    2730
#define DFF1_   5460
#define KF_     1056      // fourier K padded (1025 -> 1056)
#define KM_     2752      // geglu-mid K padded (2730 -> 2752)
#define SCALE_  0.125f
#define TWO_PI_ 6.28318530717958647692f

#define KSTR_   72        // K-tile LDS row stride (shorts)
#define VSTR_   72        // V^T-tile LDS row stride
#define PSTR_   68        // P-tile LDS row stride

typedef __attribute__((ext_vector_type(8))) short bfx8;   // 8 bf16 = 4 VGPR
typedef __attribute__((ext_vector_type(4))) float fx4;    // MFMA accum

__device__ __forceinline__ float b2f(unsigned short u) {
  return __uint_as_float(((unsigned)u) << 16);
}
__device__ __forceinline__ unsigned short f2b(float f) {  // RNE
  unsigned x = __float_as_uint(f);
  return (unsigned short)((x + 0x7FFF + ((x >> 16) & 1)) >> 16);
}

// ---------------------------------------------------------------- fourier -> bf16 [4096][1056], zero-padded
__global__ __launch_bounds__(256) void fourier_kernel(const float* __restrict__ times,
                                                      const float* __restrict__ fw,
                                                      unsigned short* __restrict__ F) {
  int r = blockIdx.x;
  float tv = times[r];
  unsigned short* Fr = F + (size_t)r * KF_;
  for (int c = threadIdx.x; c < KF_; c += 256) {
    float v;
    if (c == 0)          v = tv;
    else if (c <= 512)   v = sinf(tv * fw[c - 1] * TWO_PI_);
    else if (c <= 1024)  v = cosf(tv * fw[c - 513] * TWO_PI_);
    else                 v = 0.f;
    Fr[c] = f2b(v);
  }
}

// ---------------------------------------------------------------- weight transpose: W f32 [K][N] -> WT bf16 [N][KP]
__global__ __launch_bounds__(256) void transpose_w(const float* __restrict__ W,
                                                   unsigned short* __restrict__ WT,
                                                   int K, int N, int KP) {
  __shared__ float t[32][33];
  int tx = threadIdx.x, ty = threadIdx.y;    // 32 x 8
  int k0 = blockIdx.x * 32, n0 = blockIdx.y * 32;
#pragma unroll
  for (int i = 0; i < 4; ++i) {
    int k = k0 + ty + i * 8, n = n0 + tx;
    t[ty + i * 8][tx] = (k < K && n < N) ? W[(size_t)k * N + n] : 0.f;
  }
  __syncthreads();
#pragma unroll
  for (int i = 0; i < 4; ++i) {
    int n = n0 + ty + i * 8;
    if (n < N) WT[(size_t)n * KP + k0 + tx] = f2b(t[tx][ty + i * 8]);
  }
}

// ---------------------------------------------------------------- MFMA GEMM (explicit b128 staging, verified round 4)
__global__ __launch_bounds__(256) void mfma_gemm(const unsigned short* __restrict__ A,
                                                 const unsigned short* __restrict__ BT,
                                                 const float* __restrict__ bias,
                                                 void* __restrict__ Cout,
                                                 int K, int Nc, int mode, int out_bf) {
  __shared__ unsigned short As[128 * 32];
  __shared__ unsigned short Bs[128 * 32];
  int tid = threadIdx.x;
  int wave = tid >> 6, lane = tid & 63;
  int bm = blockIdx.y * 128, bn = blockIdx.x * 128;
  int wm = (wave >> 1) * 64, wn = (wave & 1) * 64;
  int lr = lane >> 4, lc = lane & 15;
  fx4 acc[4][4];
#pragma unroll
  for (int i = 0; i < 4; ++i)
#pragma unroll
    for (int j = 0; j < 4; ++j) acc[i][j] = (fx4){0.f, 0.f, 0.f, 0.f};

  for (int k0 = 0; k0 < K; k0 += 32) {
#pragma unroll
    for (int i = 0; i < 2; ++i) {
      int c = tid + i * 256;
      int row = c >> 2, kc = (c & 3) * 8;
      bfx8 av = *(const bfx8*)(A  + (size_t)(bm + row) * K + k0 + kc);
      bfx8 bv = *(const bfx8*)(BT + (size_t)(bn + row) * K + k0 + kc);
      *(bfx8*)&As[c * 8] = av;
      *(bfx8*)&Bs[c * 8] = bv;
    }
    __syncthreads();
    bfx8 af[4], bf[4];
#pragma unroll
    for (int mi = 0; mi < 4; ++mi)
      af[mi] = *(const bfx8*)&As[(wm + mi * 16 + lc) * 32 + lr * 8];
#pragma unroll
    for (int ni = 0; ni < 4; ++ni)
      bf[ni] = *(const bfx8*)&Bs[(wn + ni * 16 + lc) * 32 + lr * 8];
#pragma unroll
    for (int mi = 0; mi < 4; ++mi)
#pragma unroll
      for (int ni = 0; ni < 4; ++ni)
        acc[mi][ni] = __builtin_amdgcn_mfma_f32_16x16x32_bf16(af[mi], bf[ni], acc[mi][ni], 0, 0, 0);
    __syncthreads();
  }
#pragma unroll
  for (int mi = 0; mi < 4; ++mi) {
#pragma unroll
    for (int ni = 0; ni < 4; ++ni) {
      int col = bn + wn + ni * 16 + lc;
      if (col >= Nc) continue;
      float bv = (mode >= 1) ? bias[col] : 0.f;
#pragma unroll
      for (int r = 0; r < 4; ++r) {
        int row = bm + wm + mi * 16 + lr * 4 + r;
        float v = acc[mi][ni][r] + bv;
        if (mode == 2)      v = v / (1.f + __expf(-v));
        else if (mode == 3) v = 1.f / (1.f + __expf(-v));
        if (out_bf) ((unsigned short*)Cout)[(size_t)row * Nc + col] = f2b(v);
        else        ((float*)Cout)[(size_t)row * Nc + col] = v;
      }
    }
  }
}

// ---------------------------------------------------------------- ismod
__global__ __launch_bounds__(256) void ismod_kernel(const int* __restrict__ mp,
                                                    float* __restrict__ ismod) {
  int idx = blockIdx.x * 256 + threadIdx.x;
  int b = idx >> 11, n = idx & 2047;
  const int* p = mp + b * 6;
  bool m = false;
#pragma unroll
  for (int mi = 0; mi < 2; ++mi) {
    int off = p[mi * 3 + 1], len = p[mi * 3 + 2];
    m = m || ((n >= off) && (n < off + len));
  }
  ismod[idx] = m ? 1.f : 0.f;
}

// ---------------------------------------------------------------- layernorm f32->f32
__global__ __launch_bounds__(256) void layernorm_kernel(const float* __restrict__ X,
                                                        float* __restrict__ Y) {
  int r = blockIdx.x;
  const float* xr = X + (size_t)r * DIM_;
  float s = 0.f, ss = 0.f;
  for (int c = threadIdx.x; c < DIM_; c += 256) { float v = xr[c]; s += v; ss += v * v; }
#pragma unroll
  for (int o = 32; o > 0; o >>= 1) { s += __shfl_down(s, o); ss += __shfl_down(ss, o); }
  __shared__ float shs[4], shss[4];
  int w = threadIdx.x >> 6;
  if ((threadIdx.x & 63) == 0) { shs[w] = s; shss[w] = ss; }
  __syncthreads();
  float mu = (shs[0] + shs[1] + shs[2] + shs[3]) * (1.f / DIM_);
  float var = (shss[0] + shss[1] + shss[2] + shss[3]) * (1.f / DIM_) - mu * mu;
  float rstd = rsqrtf(var + 1e-5f);
  for (int c = threadIdx.x; c < DIM_; c += 256)
    Y[(size_t)r * DIM_ + c] = (xr[c] - mu) * rstd;
}

// ---------------------------------------------------------------- modulate
__global__ __launch_bounds__(256) void modulate_kernel(float* __restrict__ H,
                                                       const float* __restrict__ film,
                                                       const float* __restrict__ lng,
                                                       const float* __restrict__ ismod) {
  int idx = blockIdx.x * 256 + threadIdx.x;
  int r = idx >> 10, c = idx & 1023;
  float h = H[idx];
  float g = film[(size_t)r * 2048 + c];
  float bt = film[(size_t)r * 2048 + 1024 + c];
  H[idx] = (ismod[r] != 0.f) ? (h * (g + 1.f) + bt) : (h * (lng[c] + 1.f));
}

// ---------------------------------------------------------------- rmsnorm (Yb bf16 or Yf f32)
__global__ __launch_bounds__(256) void rmsnorm_kernel(const float* __restrict__ X,
                                                      const float* __restrict__ g,
                                                      unsigned short* __restrict__ Yb,
                                                      float* __restrict__ Yf) {
  int r = blockIdx.x;
  const float* xr = X + (size_t)r * DIM_;
  float ss = 0.f;
  for (int c = threadIdx.x; c < DIM_; c += 256) { float v = xr[c]; ss += v * v; }
#pragma unroll
  for (int o = 32; o > 0; o >>= 1) ss += __shfl_down(ss, o);
  __shared__ float shss[4];
  int w = threadIdx.x >> 6;
  if ((threadIdx.x & 63) == 0) shss[w] = ss;
  __syncthreads();
  float tots = shss[0] + shss[1] + shss[2] + shss[3];
  float scale = 32.f / fmaxf(sqrtf(tots), 1e-12f);
  for (int c = threadIdx.x; c < DIM_; c += 256) {
    float v = xr[c] * scale * (g[c] + 1.f);
    if (Yb) Yb[(size_t)r * DIM_ + c] = f2b(v);
    else    Yf[(size_t)r * DIM_ + c] = v;
  }
}

// ---------------------------------------------------------------- rotary on bf16 qkv [ROWS_][3072] (q,k halves), fp32 math
__global__ __launch_bounds__(256) void rotary_kernel(unsigned short* __restrict__ QKV,
                                                     const float* __restrict__ rot) {
  int idx = blockIdx.x * 256 + threadIdx.x;   // ROWS_*1024 pairs
  int r = idx >> 10;
  int c0 = (idx & 1023) * 2;                  // 0..2046
  float f = rot[(r & 2047) * 64 + (c0 & 63)];
  float cs = cosf(f), sn = sinf(f);
  unsigned* p = (unsigned*)(QKV + (size_t)r * 3072 + c0);
  unsigned v = *p;
  float x0 = b2f((unsigned short)(v & 0xFFFF));
  float x1 = b2f((unsigned short)(v >> 16));
  float y0 = x0 * cs - x1 * sn;
  float y1 = x1 * cs + x0 * sn;
  *p = (unsigned)f2b(y0) | ((unsigned)f2b(y1) << 16);
}

// ---------------------------------------------------------------- MFMA flash attention
// block: 256 thr = 4 waves; wave handles 16 q rows. grid (32 qblocks, 32 b*h).
__global__ __launch_bounds__(256) void attn_kernel(const unsigned short* __restrict__ QKV,
                                                   const int* __restrict__ mp,
                                                   unsigned short* __restrict__ O) {
  __shared__ unsigned short Ks[64 * KSTR_];     // [key][d]
  __shared__ unsigned short Vt[64 * VSTR_];     // [d][key]
  __shared__ unsigned short Ps[4][16 * PSTR_];  // per-wave P [row][key]
  int bh = blockIdx.y;
  int b = bh >> 4, h = bh & 15;
  int qb = blockIdx.x;
  int tid = threadIdx.x, wave = tid >> 6, lane = tid & 63;
  int lg = lane >> 4, ln = lane & 15;
  int off0 = mp[b * 6 + 1], end0 = off0 + mp[b * 6 + 2];
  int off1 = mp[b * 6 + 4], end1 = off1 + mp[b * 6 + 5];
  int qmax = qb * 64 + 63;

  // Q A-fragments: m = ln -> q row qb*64 + wave*16 + ln
  int qrow = qb * 64 + wave * 16 + ln;
  bfx8 qf0 = *(const bfx8*)(QKV + (size_t)(b * N_ + qrow) * 3072 + h * 64 + lg * 8);
  bfx8 qf1 = *(const bfx8*)(QKV + (size_t)(b * N_ + qrow) * 3072 + h * 64 + 32 + lg * 8);

  fx4 od[4];
#pragma unroll
  for (int i = 0; i < 4; ++i) od[i] = (fx4){0.f, 0.f, 0.f, 0.f};
  float m_[4] = {-3.0e38f, -3.0e38f, -3.0e38f, -3.0e38f};
  float l_[4] = {0.f, 0.f, 0.f, 0.f};
  // output rows owned by this lane: i_[reg] = qb*64 + wave*16 + lg*4 + reg
  int ibase = qb * 64 + wave * 16 + lg * 4;

  for (int jt = 0; jt < 32; ++jt) {
    int j0 = jt * 64;
    if (!((j0 <= qmax) || (qmax >= off0 && j0 < end0) || (qmax >= off1 && j0 < end1))) continue;
    __syncthreads();
    // stage K [key][d]
    for (int e = tid; e < 512; e += 256) {
      int jj = e >> 3, dc = (e & 7) * 8;
      *(bfx8*)&Ks[jj * KSTR_ + dc] =
          *(const bfx8*)(QKV + (size_t)(b * N_ + j0 + jj) * 3072 + 1024 + h * 64 + dc);
    }
    // stage V^T [d][key]
    {
      int key = tid & 63, db = (tid >> 6) * 16;
      const unsigned short* vr = QKV + (size_t)(b * N_ + j0 + key) * 3072 + 2048 + h * 64 + db;
      bfx8 v0 = *(const bfx8*)vr;
      bfx8 v1 = *(const bfx8*)(vr + 8);
#pragma unroll
      for (int t = 0; t < 8; ++t) {
        Vt[(db + t) * VSTR_ + key]     = (unsigned short)v0[t];
        Vt[(db + 8 + t) * VSTR_ + key] = (unsigned short)v1[t];
      }
    }
    __syncthreads();
    // QK^T: S[16 q][64 key]
    fx4 sf[4];
#pragma unroll
    for (int kn = 0; kn < 4; ++kn) {
      fx4 a = (fx4){0.f, 0.f, 0.f, 0.f};
      bfx8 b0 = *(const bfx8*)&Ks[(kn * 16 + ln) * KSTR_ + lg * 8];
      bfx8 b1 = *(const bfx8*)&Ks[(kn * 16 + ln) * KSTR_ + 32 + lg * 8];
      a = __builtin_amdgcn_mfma_f32_16x16x32_bf16(qf0, b0, a, 0, 0, 0);
      a = __builtin_amdgcn_mfma_f32_16x16x32_bf16(qf1, b1, a, 0, 0, 0);
      sf[kn] = a;
    }
    // softcap + mask (C-layout: row = lg*4+reg, col = kn*16+ln)
    float sv[4][4];
#pragma unroll
    for (int kn = 0; kn < 4; ++kn) {
      int j = j0 + kn * 16 + ln;
#pragma unroll
      for (int reg = 0; reg < 4; ++reg) {
        int i = ibase + reg;
        float s = sf[kn][reg] * SCALE_;
        float xc = fminf(fmaxf(s * 0.02f, -15.f), 15.f);
        float e2 = __expf(2.f * xc);
        s = 50.f * (e2 - 1.f) / (e2 + 1.f);
        bool ok = (i >= j) || (i >= off0 && j < end0) || (i >= off1 && j < end1);
        sv[kn][reg] = ok ? s : -1.0e30f;
      }
    }
    // online softmax per row: butterfly over the 16 lanes sharing each row
    float tm[4];
#pragma unroll
    for (int reg = 0; reg < 4; ++reg)
      tm[reg] = fmaxf(fmaxf(sv[0][reg], sv[1][reg]), fmaxf(sv[2][reg], sv[3][reg]));
#pragma unroll
    for (int x = 1; x < 16; x <<= 1)
#pragma unroll
      for (int reg = 0; reg < 4; ++reg) tm[reg] = fmaxf(tm[reg], __shfl_xor(tm[reg], x));
    float scl[4];
#pragma unroll
    for (int reg = 0; reg < 4; ++reg) {
      float mn = fmaxf(m_[reg], tm[reg]);
      scl[reg] = __expf(m_[reg] - mn);
      m_[reg] = mn;
    }
    float ts[4] = {0.f, 0.f, 0.f, 0.f};
#pragma unroll
    for (int kn = 0; kn < 4; ++kn)
#pragma unroll
      for (int reg = 0; reg < 4; ++reg) {
        float pp = __expf(sv[kn][reg] - m_[reg]);
        sv[kn][reg] = pp;
        ts[reg] += pp;
      }
#pragma unroll
    for (int x = 1; x < 16; x <<= 1)
#pragma unroll
      for (int reg = 0; reg < 4; ++reg) ts[reg] += __shfl_xor(ts[reg], x);
#pragma unroll
    for (int reg = 0; reg < 4; ++reg) l_[reg] = l_[reg] * scl[reg] + ts[reg];
    // P -> LDS (C-layout scatter), re-read as A-fragments
#pragma unroll
    for (int kn = 0; kn < 4; ++kn)
#pragma unroll
      for (int reg = 0; reg < 4; ++reg)
        Ps[wave][(lg * 4 + reg) * PSTR_ + kn * 16 + ln] = f2b(sv[kn][reg]);
    // rescale O
#pragma unroll
    for (int dn = 0; dn < 4; ++dn)
#pragma unroll
      for (int reg = 0; reg < 4; ++reg) od[dn][reg] *= scl[reg];
    bfx8 pf0 = *(const bfx8*)&Ps[wave][ln * PSTR_ + lg * 8];
    bfx8 pf1 = *(const bfx8*)&Ps[wave][ln * PSTR_ + 32 + lg * 8];
#pragma unroll
    for (int dn = 0; dn < 4; ++dn) {
      bfx8 v0 = *(const bfx8*)&Vt[(dn * 16 + ln) * VSTR_ + lg * 8];
      bfx8 v1 = *(const bfx8*)&Vt[(dn * 16 + ln) * VSTR_ + 32 + lg * 8];
      od[dn] = __builtin_amdgcn_mfma_f32_16x16x32_bf16(pf0, v0, od[dn], 0, 0, 0);
      od[dn] = __builtin_amdgcn_mfma_f32_16x16x32_bf16(pf1, v1, od[dn], 0, 0, 0);
    }
  }
  // write O rows: (row = ibase+reg, col = h*64 + dn*16+ln)
#pragma unroll
  for (int reg = 0; reg < 4; ++reg) {
    float inv = 1.f / l_[reg];
    unsigned short* orow = O + (size_t)(b * N_ + ibase + reg) * 1024 + h * 64;
#pragma unroll
    for (int dn = 0; dn < 4; ++dn)
      orow[dn * 16 + ln] = f2b(od[dn][reg] * inv);
  }
}

// ---------------------------------------------------------------- geglu: ff1 chunk f32 [1024][5460] -> mid bf16 (stride 2752)
__global__ __launch_bounds__(256) void geglu_kernel(const float* __restrict__ FF1,
                                                    unsigned short* __restrict__ MID) {
  int c = blockIdx.x * 256 + threadIdx.x;
  int r = blockIdx.y;
  if (c >= KM_) return;
  unsigned short outv = 0;
  if (c < DFF_) {
    float u = FF1[(size_t)r * DFF1_ + c];
    float g = FF1[(size_t)r * DFF1_ + DFF_ + c];
    float ge = 0.5f * g * (1.f + erff(g * 0.70710678118654752440f));
    outv = f2b(ge * u);
  }
  MID[(size_t)r * KM_ + c] = outv;
}

// ---------------------------------------------------------------- residual
__global__ __launch_bounds__(256) void residual_kernel(float* __restrict__ X,
                                                       const float* __restrict__ outb,
                                                       const float* __restrict__ gate,
                                                       const float* __restrict__ ls,
                                                       const float* __restrict__ ismod) {
  int idx = blockIdx.x * 256 + threadIdx.x;
  int r = idx >> 10, c = idx & 1023;
  float ov = outb[idx];
  float v = (ismod[r] != 0.f) ? (ov * gate[idx]) : (ov * (ls[c] + 1.f));
  X[idx] += v;
}

// ================================================================ launch
extern "C" void kernel_launch(void* const* d_in, const int* in_sizes, int n_in,
                              void* d_out, int out_size, void* d_ws, size_t ws_size,
                              hipStream_t stream) {
  const float* in_x   = (const float*)d_in[0];
  const float* times  = (const float*)d_in[1];
  const float* rotary = (const float*)d_in[2];
  const float* fwgt   = (const float*)d_in[3];
  const float* time_w = (const float*)d_in[4];
  const float* time_b = (const float*)d_in[5];
  const float* afw    = (const float*)d_in[6];
  const float* afb    = (const float*)d_in[7];
  const float* azw    = (const float*)d_in[8];
  const float* azb    = (const float*)d_in[9];
  const float* alng   = (const float*)d_in[10];
  const float* als    = (const float*)d_in[11];
  const float* armsg  = (const float*)d_in[12];
  const float* wqkv   = (const float*)d_in[13];
  const float* wout   = (const float*)d_in[14];
  const float* ffw    = (const float*)d_in[15];
  const float* ffb    = (const float*)d_in[16];
  const float* fzw    = (const float*)d_in[17];
  const float* fzb    = (const float*)d_in[18];
  const float* flng   = (const float*)d_in[19];
  const float* fls    = (const float*)d_in[20];
  const float* frmsg  = (const float*)d_in[21];
  const float* fw1    = (const float*)d_in[22];
  const float* fb1    = (const float*)d_in[23];
  const float* fw2    = (const float*)d_in[24];
  const float* fb2    = (const float*)d_in[25];
  const float* fing   = (const float*)d_in[26];
  const int*   mp     = (const int*)d_in[27];
  float* out = (float*)d_out;

  char* p = (char*)d_ws;
  unsigned short* wT   = (unsigned short*)p;      p += 17301504;
  float* f_x           = (float*)p;               p += 16777216;
  float* f_ln          = (float*)p;               p += 16777216;
  float* f_o           = (float*)p;               p += 16777216;
  unsigned short* cond = (unsigned short*)p;      p += 33554432;  // [4096][4096] bf16
  unsigned short* hbf  = (unsigned short*)p;      p += 8388608;   // [4096][1024] bf16
  float* film          = (float*)p;               p += 33554432;  // [4096][2048] f32
  float* gate          = (float*)p;               p += 16777216;  // [4096][1024] f32
  char* arena          = p;                       p += 58720256;
  float* f_ismod       = (float*)p;               p += 16384;

  unsigned short* qkv    = (unsigned short*)arena;              // [4096][3072] bf16 (25.2 MB)
  unsigned short* attno  = (unsigned short*)(arena + 50331648); // [4096][1024] bf16 (8.4 MB)
  float* ff1c            = (float*)arena;                       // [1024][5460] f32 chunk (22.4 MB)
  unsigned short* mid    = (unsigned short*)(arena + 22364160); // [4096][2752] bf16 (22.5 MB)
  unsigned short* four   = (unsigned short*)arena;              // [4096][1056] bf16

  auto gemm = [&](const unsigned short* A, const float* bias, void* C,
                  int K, int Nc, int mode, int out_bf, int mtiles) {
    mfma_gemm<<<dim3((Nc + 127) / 128, mtiles), 256, 0, stream>>>(A, wT, bias, C, K, Nc, mode, out_bf);
  };
  auto transp = [&](const float* W, int K, int N, int KP) {
    transpose_w<<<dim3(KP / 32, (N + 31) / 32), dim3(32, 8), 0, stream>>>(W, wT, K, N, KP);
  };

  // ---- conditioning ----
  fourier_kernel<<<ROWS_, 256, 0, stream>>>(times, fwgt, four);
  transp(time_w, 1025, DCOND_, KF_);
  gemm(four, time_b, cond, KF_, DCOND_, 2, 1, 32);
  ismod_kernel<<<ROWS_ / 256, 256, 0, stream>>>(mp, f_ismod);
  hipMemcpyAsync(f_x, in_x, (size_t)ROWS_ * DIM_ * sizeof(float),
                 hipMemcpyDeviceToDevice, stream);

  for (int l = 0; l < 2; ++l) {
    // ---- attention block ----
    layernorm_kernel<<<ROWS_, 256, 0, stream>>>(f_x, f_ln);
    transp(afw + (size_t)l * DCOND_ * 2048, DCOND_, 2048, DCOND_);
    gemm(cond, afb + l * 2048, film, DCOND_, 2048, 1, 0, 32);
    modulate_kernel<<<(ROWS_ * DIM_) / 256, 256, 0, stream>>>(f_ln, film, alng + l * 1024, f_ismod);
    rmsnorm_kernel<<<ROWS_, 256, 0, stream>>>(f_ln, armsg + l * 1024, hbf, nullptr);
    transp(wqkv + (size_t)l * 1024 * 3072, 1024, 3072, 1024);
    gemm(hbf, nullptr, qkv, 1024, 3072, 0, 1, 32);
    rotary_kernel<<<(ROWS_ * 1024) / 256, 256, 0, stream>>>(qkv, rotary);
    attn_kernel<<<dim3(32, 32), 256, 0, stream>>>(qkv, mp, attno);
    transp(wout + (size_t)l * 1024 * 1024, 1024, 1024, 1024);
    gemm(attno, nullptr, f_o, 1024, 1024, 0, 0, 32);
    transp(azw + (size_t)l * DCOND_ * 1024, DCOND_, 1024, DCOND_);
    gemm(cond, azb + l * 1024, gate, DCOND_, 1024, 3, 0, 32);
    residual_kernel<<<(ROWS_ * DIM_) / 256, 256, 0, stream>>>(f_x, f_o, gate, als + l * 1024, f_ismod);

    // ---- feed-forward block ----
    layernorm_kernel<<<ROWS_, 256, 0, stream>>>(f_x, f_ln);
    transp(ffw + (size_t)l * DCOND_ * 2048, DCOND_, 2048, DCOND_);
    gemm(cond, ffb + l * 2048, film, DCOND_, 2048, 1, 0, 32);
    modulate_kernel<<<(ROWS_ * DIM_) / 256, 256, 0, stream>>>(f_ln, film, flng + l * 1024, f_ismod);
    rmsnorm_kernel<<<ROWS_, 256, 0, stream>>>(f_ln, frmsg + l * 1024, hbf, nullptr);
    transp(fw1 + (size_t)l * 1024 * DFF1_, 1024, DFF1_, 1024);
    for (int rc = 0; rc < 4; ++rc) {
      gemm(hbf + (size_t)rc * 1024 * 1024, fb1 + l * DFF1_, ff1c, 1024, DFF1_, 1, 0, 8);
      geglu_kernel<<<dim3((KM_ + 255) / 256, 1024), 256, 0, stream>>>(
          ff1c, mid + (size_t)rc * 1024 * KM_);
    }
    transp(fw2 + (size_t)l * DFF_ * 1024, DFF_, 1024, KM_);
    gemm(mid, fb2 + l * 1024, f_o, KM_, 1024, 1, 0, 32);
    transp(fzw + (size_t)l * DCOND_ * 1024, DCOND_, 1024, DCOND_);
    gemm(cond, fzb + l * 1024, gate, DCOND_, 1024, 3, 0, 32);
    residual_kernel<<<(ROWS_ * DIM_) / 256, 256, 0, stream>>>(f_x, f_o, gate, fls + l * 1024, f_ismod);
  }

  // final rmsnorm -> fp32 out
  rmsnorm_kernel<<<ROWS_, 256, 0, stream>>>(f_x, fing, nullptr, out);
}